// Round 6
// baseline (1326.229 us; speedup 1.0000x reference)
//
#include <hip/hip_runtime.h>
#include <math.h>

#define B 2
#define Q 15
#define U 20
#define C 64
#define HW 441
#define NW 5
#define MU (U*HW)      // 8820
#define MS HW          // 441
#define NJ (NW*MS)     // 2205
#define PD 64
#define LCAP NJ
#define LTCAP 2688     // 42*64 >= 441+2205
#define MSP 448
#define NEGF (-3.402823466e38f)

// ---------------- device scratch (rewritten every call before any read) -----
__device__ float g_rnu[B*MU];
__device__ float g_rns[B*NJ];
__device__ unsigned long long g_snearpack[B*NJ];
__device__ unsigned long long g_unearpack[B*MU];
__device__ int   g_counts[B*NW];
__device__ int   g_L[1];
__device__ int   g_selidx[B*NW*LCAP];
__device__ float g_ksup[(size_t)B*NW*PD*LTCAP];
__device__ float g_vsup[(size_t)B*NW*PD*LTCAP];
__device__ float g_vbarn[B*NW*PD];
__device__ float g_qproj[(size_t)B*Q*PD*MSP];
__device__ float g_qprojc[(size_t)B*Q*PD*MSP];   // masked rows compacted, zero-padded
__device__ float g_vqn[(size_t)B*Q*PD*MSP];
__device__ unsigned long long g_rowpack[(size_t)B*Q*NW*MSP];
__device__ unsigned long long g_snear2pack[(size_t)B*Q*NW*LTCAP];
__device__ int   g_qmrows[B*Q*MSP];
__device__ int   g_qmcount[B*Q];
__device__ unsigned g_cmax[(size_t)B*Q*NW*MSP];
__device__ float g_logits[B*Q*NW];

__device__ __forceinline__ unsigned enc_f(float f){
  unsigned b=__float_as_uint(f);
  return (b&0x80000000u)? ~b : (b|0x80000000u);
}
__device__ __forceinline__ float dec_f(unsigned k){
  unsigned b=(k&0x80000000u)?(k^0x80000000u):~k;
  return __uint_as_float(b);
}
__device__ __forceinline__ unsigned long long pk_make(float v,int idx){
  return ((unsigned long long)enc_f(v)<<32)|(unsigned)~(unsigned)idx;
}
__device__ __forceinline__ int pk_idx(unsigned long long p){
  return (int)~(unsigned)(p&0xFFFFFFFFull);
}

// ---------------- init ------------------------------------------------------
__global__ void k_init(){
  int i=blockIdx.x*256+threadIdx.x;
  if (i<B*NJ) g_snearpack[i]=0ull;
  if (i<B*MU) g_unearpack[i]=0ull;
  if (i<B*Q*NW*MSP){ g_rowpack[i]=0ull; g_cmax[i]=0u; }
  if (i<B*Q*NW*LTCAP) g_snear2pack[i]=0ull;
  if (i==0) g_L[0]=0;
}

// ---------------- K1: inverse column norms ---------------------------------
__global__ void k_norms(const float* __restrict__ sup, const float* __restrict__ unl){
  int i=blockIdx.x*256+threadIdx.x;
  if (i<B*MU){
    int b=i/MU, m=i%MU, ui=m/HW, p=m%HW;
    const float* base=unl+((size_t)(b*U+ui)*C)*HW+p;
    float ss=0.f;
    for (int c=0;c<C;c++){ float x=base[(size_t)c*HW]; ss+=x*x; }
    g_rnu[i]=1.f/fmaxf(sqrtf(ss),1e-12f);
  }
  if (i<B*NJ){
    int b=i/NJ, j=i%NJ, n=j/MS, s=j%MS;
    const float* base=sup+((size_t)(b*NW+n)*C)*HW+s;
    float ss=0.f;
    for (int c=0;c<C;c++){ float x=base[(size_t)c*HW]; ss+=x*x; }
    g_rns[i]=1.f/fmaxf(sqrtf(ss),1e-12f);
  }
}

// ---------------- K2: u2s — col-split 6x; 64x128 tiles; shuffle argmaxes ----
__global__ __launch_bounds__(256) void k_u2s(const float* __restrict__ sup, const float* __restrict__ unl){
  int blk=blockIdx.x;
  int grp=blk%6; blk/=6;
  int rb=blk%138; int b=blk/138;
  int mb=rb*64;
  int tid=threadIdx.x, tm=tid>>4, tl=tid&15;
  int lane=tid&63, w=tid>>6;
  __shared__ __align__(16) float Ut[4096];     // [c][m] 16KB
  __shared__ __align__(16) float Pt[8192];     // [c][j] 32KB
  __shared__ unsigned long long colred[512];   // [w][128] 4KB
  int mv=min(64,MU-mb);
  for (int k=tid;k<4096;k+=256){
    int c=k>>6, mm=k&63; float v=0.f;
    if (mm<mv){ int m=mb+mm, ui=m/HW, p=m%HW; v=unl[((size_t)(b*U+ui)*C+c)*HW+p]*g_rnu[b*MU+m]; }
    Ut[c*64+mm]=v;
  }
  unsigned long long rowpk[4]={0ull,0ull,0ull,0ull};
  for (int t=0;t<3;t++){
    int j0=(grp*3+t)*128;
    int jv=min(128,NJ-j0);
    __syncthreads();
    for (int k=tid;k<8192;k+=256){
      int c=k>>7, jj=k&127; float v=0.f;
      if (jj<jv){ int j=j0+jj, n=j/MS, s=j%MS; v=sup[((size_t)(b*NW+n)*C+c)*HW+s]*g_rns[b*NJ+j]; }
      Pt[c*128+jj]=v;
    }
    __syncthreads();
    float s[4][8]={};
    for (int c=0;c<64;c++){
      float a[4],b0[4],b1[4];
      *(float4*)a =*(const float4*)&Ut[c*64+tm*4];
      *(float4*)b0=*(const float4*)&Pt[c*128+tl*4];
      *(float4*)b1=*(const float4*)&Pt[c*128+64+tl*4];
      #pragma unroll
      for (int i=0;i<4;i++)
        #pragma unroll
        for (int j=0;j<4;j++){ s[i][j]=fmaf(a[i],b0[j],s[i][j]); s[i][j+4]=fmaf(a[i],b1[j],s[i][j+4]); }
    }
    #pragma unroll
    for (int i=0;i<4;i++){
      if (tm*4+i<mv){
        unsigned long long p=rowpk[i];
        #pragma unroll
        for (int j=0;j<8;j++){
          int jj=(j<4)?(tl*4+j):(64+tl*4+(j-4));
          if (jj<jv){
            unsigned long long c2=pk_make(s[i][j],j0+jj);
            if (c2>p) p=c2;
          }
        }
        rowpk[i]=p;
      }
    }
    unsigned long long cpk[8];
    #pragma unroll
    for (int j=0;j<8;j++){
      unsigned long long p=0ull;
      #pragma unroll
      for (int i=0;i<4;i++){
        if (tm*4+i<mv){
          unsigned long long c2=pk_make(s[i][j],mb+tm*4+i);
          if (c2>p) p=c2;
        }
      }
      cpk[j]=p;
    }
    #pragma unroll
    for (int j=0;j<8;j++){
      unsigned long long o;
      o=__shfl_xor(cpk[j],16); if (o>cpk[j]) cpk[j]=o;
      o=__shfl_xor(cpk[j],32); if (o>cpk[j]) cpk[j]=o;
    }
    if ((lane>>4)==0){
      #pragma unroll
      for (int j=0;j<8;j++){
        int jj=(j<4)?(tl*4+j):(64+tl*4+(j-4));
        colred[w*128+jj]=cpk[j];
      }
    }
    __syncthreads();
    if (tid<128 && tid<jv){
      unsigned long long p=colred[tid];
      if (colred[128+tid]>p) p=colred[128+tid];
      if (colred[256+tid]>p) p=colred[256+tid];
      if (colred[384+tid]>p) p=colred[384+tid];
      if (p) atomicMax(&g_snearpack[b*NJ+j0+tid],p);
    }
  }
  #pragma unroll
  for (int i=0;i<4;i++){
    unsigned long long p=rowpk[i];
    #pragma unroll
    for (int mk=1;mk<16;mk<<=1){ unsigned long long o=__shfl_xor(p,mk); if (o>p) p=o; }
    if (tl==0 && tm*4+i<mv && p) atomicMax(&g_unearpack[b*MU+mb+tm*4+i],p);
  }
}

// ---------------- K4: mutual check + stable compaction; counts; L ----------
__global__ __launch_bounds__(256) void k_compact(){
  int b=blockIdx.x/NW, n=blockIdx.x%NW;
  int tid=threadIdx.x, lane=tid&63, w=tid>>6;
  __shared__ int wtot[4];
  int base=0;
  for (int m0=0;m0<MU;m0+=256){
    int m=m0+tid;
    bool flag=false;
    if (m<MU){
      int j=pk_idx(g_unearpack[b*MU+m]);
      flag=(j/MS==n) && (pk_idx(g_snearpack[b*NJ+j])==m);
    }
    unsigned long long bal=__ballot(flag);
    if (lane==0) wtot[w]=(int)__popcll(bal);
    __syncthreads();
    int wpre=0, tot=0;
    #pragma unroll
    for (int ww=0;ww<4;ww++){ if (ww<w) wpre+=wtot[ww]; tot+=wtot[ww]; }
    if (flag){
      int pre=(int)__popcll(bal&((1ull<<lane)-1ull));
      g_selidx[(b*NW+n)*LCAP+base+wpre+pre]=m;
    }
    base+=tot;
    __syncthreads();
  }
  if (tid==0){ g_counts[b*NW+n]=base; atomicMax(&g_L[0],base); }
}

// ---------------- K5: k_sup / v_sup (real cols only; o-split x2) ------------
__global__ __launch_bounds__(256) void k_kv(const float* __restrict__ sup, const float* __restrict__ unl,
                                            const float* __restrict__ kw, const float* __restrict__ vw){
  int blk=blockIdx.x;
  int os=blk&1; blk>>=1;
  int lb=blk%(LTCAP/64); blk/=(LTCAP/64);
  int n=blk%NW, b=blk/NW;
  int cnt=g_counts[b*NW+n];
  if (lb*64>=MS+cnt) return;
  int tid=threadIdx.x, lane=tid&63, w=tid>>6;
  __shared__ float F[4096];
  __shared__ const float* ptr_s[64];
  if (tid<64){
    int l=lb*64+tid;
    const float* p=nullptr;
    if (l<MS) p=&sup[((size_t)(b*NW+n)*C)*HW+l];
    else if (l<MS+cnt){
      int mg=g_selidx[(b*NW+n)*LCAP+(l-MS)];
      int ui=mg/HW, pp=mg%HW;
      p=&unl[((size_t)(b*U+ui)*C)*HW+pp];
    }
    ptr_s[tid]=p;
  }
  __syncthreads();
  for (int k=tid;k<4096;k+=256){
    int c=k>>6, ll=k&63;
    const float* p=ptr_s[ll];
    F[c*64+ll]=p?p[(size_t)c*HW]:0.f;
  }
  __syncthreads();
  int l=lb*64+lane;
  size_t ob=((size_t)(b*NW+n)*PD)*LTCAP+l;
  for (int oo=0;oo<8;oo++){
    int o=os*32+w*8+oo;
    float ka=0.f, va=0.f;
    for (int c=0;c<C;c++){ float f=F[c*64+lane]; ka=fmaf(kw[o*C+c],f,ka); va=fmaf(vw[o*C+c],f,va); }
    g_ksup[ob+(size_t)o*LTCAP]=ka;
    g_vsup[ob+(size_t)o*LTCAP]=va;
  }
}

// ---------------- K5b: normalized vbar = mean_l v_sup, L2-normalized --------
__global__ __launch_bounds__(256) void k_vbar(){
  int bn=blockIdx.x;
  int tid=threadIdx.x, lane=tid&63, w=tid>>6;
  int cnt=g_counts[bn];
  int Lt=MS+g_L[0];
  __shared__ float vb_s[64];
  for (int oo=0;oo<16;oo++){
    int o=w*16+oo;
    const float* row=&g_vsup[((size_t)bn*PD+o)*LTCAP];
    float s=0.f;
    for (int l=lane;l<MS+cnt;l+=64) s+=row[l];
    #pragma unroll
    for (int mk=1;mk<64;mk<<=1) s+=__shfl_xor(s,mk);
    if (lane==0) vb_s[o]=s/(float)Lt;
  }
  __syncthreads();
  if (tid<64){
    float v=vb_s[tid];
    float ss=v*v;
    #pragma unroll
    for (int mk=1;mk<64;mk<<=1) ss+=__shfl_xor(ss,mk);
    g_vbarn[bn*PD+tid]=v/(sqrtf(ss)+1e-16f);
  }
}

// ---------------- K6: q_proj / normalized v_query (256 thr, o-split) --------
__global__ __launch_bounds__(256) void k_qproj(const float* __restrict__ qx, const float* __restrict__ qw,
                                               const float* __restrict__ vw){
  int blk=blockIdx.x;
  int mt=blk%7; blk/=7;
  int bq=blk;
  int tid=threadIdx.x, lane=tid&63, w=tid>>6;
  __shared__ float F[4096];
  __shared__ float ssp[256];
  for (int k=tid;k<4096;k+=256){
    int c=k>>6, mm=k&63, m=mt*64+mm;
    F[c*64+mm]=(m<MS)?qx[((size_t)bq*C+c)*HW+m]:0.f;
  }
  __syncthreads();
  int m=mt*64+lane;
  size_t ob=(size_t)bq*PD*MSP+m;
  float va[16]; float ssl=0.f;
  for (int oo=0;oo<16;oo++){
    int o=w*16+oo;
    float qa=0.f, v=0.f;
    for (int c=0;c<C;c++){ float f=F[c*64+lane]; qa=fmaf(qw[o*C+c],f,qa); v=fmaf(vw[o*C+c],f,v); }
    g_qproj[ob+(size_t)o*MSP]=qa;
    va[oo]=v; ssl=fmaf(v,v,ssl);
  }
  ssp[tid]=ssl;
  __syncthreads();
  float ss=ssp[lane]+ssp[64+lane]+ssp[128+lane]+ssp[192+lane];
  float rn=1.f/(sqrtf(ss)+1e-16f);
  for (int oo=0;oo<16;oo++) g_vqn[ob+(size_t)(w*16+oo)*MSP]=va[oo]*rn;
}

// ---------------- K7: pass A — real cols only + analytic pad candidate ------
__global__ __launch_bounds__(256) void k_passA(){
  int blk=blockIdx.x;
  int mh=blk%4; blk/=4;
  int n=blk%NW; blk/=NW;
  int bq=blk; int b=bq/Q;
  int cnt=g_counts[b*NW+n];
  int Ltn=MS+cnt;
  int nch=(Ltn+63)>>6;
  int tid=threadIdx.x, tm=tid>>4, tl=tid&15;
  int lane=tid&63, w=tid>>6;
  int bqn=bq*NW+n;
  int m0=mh*128;
  __shared__ __align__(16) float Qt[8192];     // [o][mm] 32KB
  __shared__ __align__(16) float Kt[4096];     // [o][l]  16KB
  __shared__ unsigned long long colred[256];
  const size_t qb=(size_t)bq*PD*MSP;
  const size_t kb=(size_t)(b*NW+n)*PD*LTCAP;
  for (int k=tid;k<2048;k+=256){
    int o=k>>5, mq=k&31;
    int m=m0+mq*4;
    float4 v=make_float4(0.f,0.f,0.f,0.f);
    if (m<MSP) v=*(const float4*)&g_qproj[qb+(size_t)o*MSP+m];
    *(float4*)&Qt[o*128+mq*4]=v;
  }
  unsigned long long rowpk[8]={0ull,0ull,0ull,0ull,0ull,0ull,0ull,0ull};
  for (int lc=0;lc<nch;lc++){
    int l0=lc<<6, lv=min(64,Ltn-l0);
    __syncthreads();
    for (int k=tid;k<1024;k+=256){
      int o=k>>4, lq=k&15;
      *(float4*)&Kt[o*64+lq*4]=*(const float4*)&g_ksup[kb+(size_t)o*LTCAP+l0+lq*4];
    }
    __syncthreads();
    float s[8][4]={};
    for (int c=0;c<64;c++){
      float a[8],bv[4];
      *(float4*)&a[0]=*(const float4*)&Qt[c*128+tm*8];
      *(float4*)&a[4]=*(const float4*)&Qt[c*128+tm*8+4];
      *(float4*)bv=*(const float4*)&Kt[c*64+tl*4];
      #pragma unroll
      for (int i=0;i<8;i++)
        #pragma unroll
        for (int j=0;j<4;j++) s[i][j]=fmaf(a[i],bv[j],s[i][j]);
    }
    #pragma unroll
    for (int i=0;i<8;i++)
      #pragma unroll
      for (int j=0;j<4;j++) s[i][j]*=0.125f;
    #pragma unroll
    for (int i=0;i<8;i++){
      int m=m0+tm*8+i;
      if (m<MS){
        unsigned long long p=rowpk[i];
        #pragma unroll
        for (int j=0;j<4;j++){
          if (tl*4+j<lv){
            unsigned long long c2=pk_make(s[i][j],l0+tl*4+j);
            if (c2>p) p=c2;
          }
        }
        rowpk[i]=p;
      }
    }
    unsigned long long cpk[4];
    #pragma unroll
    for (int j=0;j<4;j++){
      unsigned long long p=0ull;
      #pragma unroll
      for (int i=0;i<8;i++){
        int m=m0+tm*8+i;
        if (m<MS){
          unsigned long long c2=pk_make(s[i][j],m);
          if (c2>p) p=c2;
        }
      }
      cpk[j]=p;
    }
    #pragma unroll
    for (int j=0;j<4;j++){
      unsigned long long o;
      o=__shfl_xor(cpk[j],16); if (o>cpk[j]) cpk[j]=o;
      o=__shfl_xor(cpk[j],32); if (o>cpk[j]) cpk[j]=o;
    }
    if ((lane>>4)==0){
      #pragma unroll
      for (int j=0;j<4;j++) colred[w*64+tl*4+j]=cpk[j];
    }
    __syncthreads();
    if (tid<64 && tid<lv){
      unsigned long long p=colred[tid];
      if (colred[64+tid]>p) p=colred[64+tid];
      if (colred[128+tid]>p) p=colred[128+tid];
      if (colred[192+tid]>p) p=colred[192+tid];
      if (p) atomicMax(&g_snear2pack[(size_t)bqn*LTCAP+l0+tid],p);
    }
  } // lc
  // analytic pad candidate: L-cnt all-zero columns, first at l=Ltn, value 0
  if (cnt<g_L[0]){
    unsigned long long pc=pk_make(0.0f,Ltn);
    #pragma unroll
    for (int i=0;i<8;i++){ if (pc>rowpk[i]) rowpk[i]=pc; }
  }
  #pragma unroll
  for (int i=0;i<8;i++){
    int m=m0+tm*8+i;
    unsigned long long p=rowpk[i];
    #pragma unroll
    for (int mk=1;mk<16;mk<<=1){ unsigned long long o=__shfl_xor(p,mk); if (o>p) p=o; }
    if (tl==0 && m<MS && p) atomicMax(&g_rowpack[(size_t)bqn*MSP+m],p);
  }
}

// ---------------- K8: q_mask + masked-row compaction + Q-row compaction -----
__global__ __launch_bounds__(256) void k_qmask(){
  int bq=blockIdx.x; int b=bq/Q;
  int tid=threadIdx.x, lane=tid&63, w=tid>>6;
  __shared__ int wtot[4];
  __shared__ int rows_sh[MSP];
  int base=0;
  for (int m0=0;m0<MS;m0+=256){
    int m=m0+tid;
    bool qm=false;
    if (m<MS){
      unsigned bhv=0u; unsigned long long bp=0ull; int bn=0;
      #pragma unroll
      for (int n=0;n<NW;n++){
        unsigned long long pk=g_rowpack[(size_t)(bq*NW+n)*MSP+m];
        unsigned hv=(unsigned)(pk>>32);
        if (hv>bhv){bhv=hv;bp=pk;bn=n;}
      }
      int bl=pk_idx(bp);
      int s2;
      if (bl>=MS+g_counts[b*NW+bn]) s2=0;   // all-zero pad column -> argmax m=0
      else s2=pk_idx(g_snear2pack[(size_t)(bq*NW+bn)*LTCAP+bl]);
      qm=(s2==m);
    }
    unsigned long long bal=__ballot(qm);
    if (lane==0) wtot[w]=(int)__popcll(bal);
    __syncthreads();
    int wpre=0, tot=0;
    #pragma unroll
    for (int ww=0;ww<4;ww++){ if (ww<w) wpre+=wtot[ww]; tot+=wtot[ww]; }
    if (qm){
      int pre=(int)__popcll(bal&((1ull<<lane)-1ull));
      g_qmrows[bq*MSP+base+wpre+pre]=m;
    }
    base+=tot;
    __syncthreads();
  }
  if (tid==0) g_qmcount[bq]=base;
  // ---- compact Q rows into g_qprojc (coalesced consumer layout) ----
  for (int r=tid;r<base;r+=256) rows_sh[r]=g_qmrows[bq*MSP+r];
  __syncthreads();
  int nmr=(base+63)&~63;
  size_t cb=(size_t)bq*PD*MSP;
  for (int o=0;o<PD;o++){
    const float* src=&g_qproj[cb+(size_t)o*MSP];
    float* dst=&g_qprojc[cb+(size_t)o*MSP];
    for (int rc=tid;rc<nmr;rc+=256)
      dst[rc]=(rc<base)?src[rows_sh[rc]]:0.f;
  }
}

// ---------------- K9: pass B — fixed-m* softmax, register P, fused simi2 ----
__global__ __launch_bounds__(256) void k_passB(){
  int blk=blockIdx.x;
  int rt=blk%7; blk/=7;
  int n=blk%NW; blk/=NW;
  int bq=blk; int b=bq/Q;
  int nm=g_qmcount[bq];
  if (rt*64>=nm) return;
  int bqn=bq*NW+n;
  int cnt=g_counts[b*NW+n];
  int pads=g_L[0]-cnt;
  int Ltn=MS+cnt;
  int nch=(Ltn+63)>>6;
  int tid=threadIdx.x, tm=tid>>4, tl=tid&15, lane=tid&63;
  __shared__ __align__(16) float Qt[4096];     // [o][r] 16KB
  __shared__ __align__(16) float Kt[4096];     // [o][l] 16KB (reused for vqn tiles)
  __shared__ __align__(16) float Vt[64*67];    // [l][o] stride 67 (conflict-free)
  const size_t cb=(size_t)bq*PD*MSP;
  const size_t kb=(size_t)(b*NW+n)*PD*LTCAP;
  // stage compacted Q rows (coalesced float4)
  for (int k=tid;k<1024;k+=256){
    int o=k>>4, rq=k&15;
    *(float4*)&Qt[o*64+rq*4]=*(const float4*)&g_qprojc[cb+(size_t)o*MSP+rt*64+rq*4];
  }
  // per-row softmax max (precomputed in passA's rowpack, incl. pad candidate)
  float mst[4];
  #pragma unroll
  for (int i=0;i<4;i++){
    int rc=rt*64+tm*4+i;
    float m_=0.f;
    if (rc<nm){
      int mrow=g_qmrows[bq*MSP+rc];
      m_=dec_f((unsigned)(g_rowpack[(size_t)bqn*MSP+mrow]>>32));
    }
    mst[i]=m_;
  }
  float acc[4][4]={}; float lsl[4]={0.f,0.f,0.f,0.f};
  for (int lc=0;lc<nch;lc++){
    int l0=lc<<6, lv=min(64,Ltn-l0);
    __syncthreads();
    for (int k=tid;k<1024;k+=256){
      int o=k>>4, lq=k&15;
      *(float4*)&Kt[o*64+lq*4]=*(const float4*)&g_ksup[kb+(size_t)o*LTCAP+l0+lq*4];
    }
    for (int k=tid;k<4096;k+=256){
      int o=k>>6, ll=k&63;
      Vt[ll*67+o]=g_vsup[kb+(size_t)o*LTCAP+l0+ll];
    }
    __syncthreads();
    float s[4][4]={};
    for (int c=0;c<64;c++){
      float a[4],bv[4];
      *(float4*)a =*(const float4*)&Qt[c*64+tm*4];
      *(float4*)bv=*(const float4*)&Kt[c*64+tl*4];
      #pragma unroll
      for (int i=0;i<4;i++)
        #pragma unroll
        for (int j=0;j<4;j++) s[i][j]=fmaf(a[i],bv[j],s[i][j]);
    }
    // e = exp(s/8 - m*), masked beyond lv; accumulate local denom
    #pragma unroll
    for (int i=0;i<4;i++)
      #pragma unroll
      for (int j=0;j<4;j++){
        float e=(tl*4+j<lv)?__expf(fmaf(s[i][j],0.125f,-mst[i])):0.f;
        s[i][j]=e; lsl[i]+=e;
      }
    // PV via in-register P + shuffle broadcast (no LDS round-trip)
    for (int lq=0;lq<16;lq++){
      int src=(lane&48)|lq;
      float4 vr[4];
      #pragma unroll
      for (int u=0;u<4;u++) vr[u]=*(const float4*)&Vt[(lq*4+u)*67+tl*4];
      #pragma unroll
      for (int i=0;i<4;i++){
        float p0=__shfl(s[i][0],src,64);
        float p1=__shfl(s[i][1],src,64);
        float p2=__shfl(s[i][2],src,64);
        float p3=__shfl(s[i][3],src,64);
        acc[i][0]+=p0*vr[0].x+p1*vr[1].x+p2*vr[2].x+p3*vr[3].x;
        acc[i][1]+=p0*vr[0].y+p1*vr[1].y+p2*vr[2].y+p3*vr[3].y;
        acc[i][2]+=p0*vr[0].z+p1*vr[1].z+p2*vr[2].z+p3*vr[3].z;
        acc[i][3]+=p0*vr[0].w+p1*vr[1].w+p2*vr[2].w+p3*vr[3].w;
      }
    }
  } // lc
  // finalize: denom (+ pad contribution), normalize, row L2 norm
  float rn_[4];
  #pragma unroll
  for (int i=0;i<4;i++){
    float v=lsl[i];
    #pragma unroll
    for (int mk=1;mk<16;mk<<=1) v+=__shfl_xor(v,mk);
    v+=(float)pads*__expf(-mst[i]);
    float inv=1.f/v;
    float ss=0.f;
    #pragma unroll
    for (int j=0;j<4;j++){ acc[i][j]*=inv; ss=fmaf(acc[i][j],acc[i][j],ss); }
    #pragma unroll
    for (int mk=1;mk<16;mk<<=1) ss+=__shfl_xor(ss,mk);
    rn_[i]=1.f/(sqrtf(ss)+1e-16f);
  }
  int rowok[4];
  #pragma unroll
  for (int i=0;i<4;i++) rowok[i]=(rt*64+tm*4+i<nm);
  // simi2: aligned (registers) x vqn tiles, shuffle broadcast again
  for (int kt=0;kt<7;kt++){
    __syncthreads();
    for (int k=tid;k<1024;k+=256){
      int o=k>>4, kq=k&15;
      *(float4*)&Kt[o*64+kq*4]=*(const float4*)&g_vqn[cb+(size_t)o*MSP+kt*64+kq*4];
    }
    __syncthreads();
    float d[4][4]={};
    for (int oq=0;oq<16;oq++){
      int src=(lane&48)|oq;
      float4 vr[4];
      #pragma unroll
      for (int u=0;u<4;u++) vr[u]=*(const float4*)&Kt[(oq*4+u)*64+tl*4];
      #pragma unroll
      for (int i=0;i<4;i++){
        float p0=__shfl(acc[i][0],src,64);
        float p1=__shfl(acc[i][1],src,64);
        float p2=__shfl(acc[i][2],src,64);
        float p3=__shfl(acc[i][3],src,64);
        d[i][0]+=p0*vr[0].x+p1*vr[1].x+p2*vr[2].x+p3*vr[3].x;
        d[i][1]+=p0*vr[0].y+p1*vr[1].y+p2*vr[2].y+p3*vr[3].y;
        d[i][2]+=p0*vr[0].z+p1*vr[1].z+p2*vr[2].z+p3*vr[3].z;
        d[i][3]+=p0*vr[0].w+p1*vr[1].w+p2*vr[2].w+p3*vr[3].w;
      }
    }
    #pragma unroll
    for (int j=0;j<4;j++){
      int kg2=kt*64+tl*4+j;
      float mv=NEGF;
      #pragma unroll
      for (int i=0;i<4;i++) if (rowok[i]) mv=fmaxf(mv,d[i][j]*rn_[i]);
      mv=fmaxf(mv,__shfl_xor(mv,16));
      mv=fmaxf(mv,__shfl_xor(mv,32));
      if ((lane>>4)==0 && kg2<MS && mv>-1e37f)
        atomicMax(&g_cmax[(size_t)bqn*MSP+kg2],enc_f(mv));
    }
  }
}

// ---------------- K10: logits (with fused vbar contribution) ----------------
__global__ __launch_bounds__(256) void k_logits(){
  int bqn=blockIdx.x;
  int n=bqn%NW, bq=bqn/NW, b=bq/Q;
  int tid=threadIdx.x;
  int nm=g_qmcount[bq];
  __shared__ float red[256];
  __shared__ float vb_s[64];
  if (tid<64) vb_s[tid]=g_vbarn[(b*NW+n)*PD+tid];
  __syncthreads();
  const float* vq=&g_vqn[(size_t)bq*PD*MSP];
  float p=0.f;
  for (int k=tid;k<MS;k+=256){
    float v=dec_f(g_cmax[(size_t)bqn*MSP+k]);
    if (nm<MS){
      float d=0.f;
      for (int o=0;o<PD;o++) d=fmaf(vb_s[o],vq[(size_t)o*MSP+k],d);
      v=fmaxf(v,d);
    }
    p+=(v+1.f)*0.5f;
  }
  red[tid]=p; __syncthreads();
  for (int s=128;s;s>>=1){ if (tid<s) red[tid]+=red[tid+s]; __syncthreads(); }
  if (tid==0) g_logits[bqn]=red[0];
}

// ---------------- K11: NLL loss ---------------------------------------------
__global__ void k_loss(const int* __restrict__ qy, float* __restrict__ out){
  int t=threadIdx.x;
  float lp=0.f;
  if (t<B*Q){
    int y=qy[t];
    float xv[NW]; float mxv=NEGF;
    #pragma unroll
    for (int n=0;n<NW;n++){ xv[n]=g_logits[t*NW+n]*5.f; mxv=fmaxf(mxv,xv[n]); }
    float s=0.f, xy=0.f;
    #pragma unroll
    for (int n=0;n<NW;n++){ s+=__expf(xv[n]-mxv); if (n==y) xy=xv[n]; }
    lp=xy-mxv-logf(s);
  }
  #pragma unroll
  for (int off=32;off;off>>=1) lp+=__shfl_down(lp,off);
  if (t==0) out[0]=-lp/(float)(B*Q);
}

extern "C" void kernel_launch(void* const* d_in, const int* in_sizes, int n_in,
                              void* d_out, int out_size, void* d_ws, size_t ws_size,
                              hipStream_t stream) {
  (void)in_sizes; (void)n_in; (void)out_size; (void)d_ws; (void)ws_size;
  const float* sup=(const float*)d_in[0];
  const float* qx =(const float*)d_in[2];
  const int*   qy =(const int*)d_in[3];
  const float* unl=(const float*)d_in[4];
  const float* kw =(const float*)d_in[5];
  const float* qw =(const float*)d_in[6];
  const float* vw =(const float*)d_in[7];
  float* out=(float*)d_out;

  k_init   <<<1575,256,0,stream>>>();
  k_norms  <<<69,256,0,stream>>>(sup,unl);
  k_u2s    <<<B*138*6,256,0,stream>>>(sup,unl);
  k_compact<<<B*NW,256,0,stream>>>();
  k_kv     <<<B*NW*(LTCAP/64)*2,256,0,stream>>>(sup,unl,kw,vw);
  k_vbar   <<<B*NW,256,0,stream>>>();
  k_qproj  <<<B*Q*7,256,0,stream>>>(qx,qw,vw);
  k_passA  <<<B*Q*NW*4,256,0,stream>>>();
  k_qmask  <<<B*Q,256,0,stream>>>();
  k_passB  <<<B*Q*NW*7,256,0,stream>>>();
  k_logits <<<B*Q*NW,256,0,stream>>>();
  k_loss   <<<1,64,0,stream>>>(qy,out);
}

// Round 7
// 845.969 us; speedup vs baseline: 1.5677x; 1.5677x over previous
//
#include <hip/hip_runtime.h>
#include <math.h>

#define B 2
#define Q 15
#define U 20
#define C 64
#define HW 441
#define NW 5
#define MU (U*HW)      // 8820
#define MS HW          // 441
#define NJ (NW*MS)     // 2205
#define PD 64
#define LCAP NJ
#define LTCAP 2688     // 42*64 >= 441+2205
#define MSP 448
#define NEGF (-3.402823466e38f)

// ---------------- device scratch (rewritten every call before any read) -----
__device__ float g_rnu[B*MU];
__device__ float g_rns[B*NJ];
__device__ unsigned long long g_snearpack[B*NJ];
__device__ unsigned long long g_unearpack[B*MU];
__device__ int   g_counts[B*NW];
__device__ int   g_L[1];
__device__ int   g_selidx[B*NW*LCAP];
__device__ float g_ksup[(size_t)B*NW*PD*LTCAP];
__device__ float g_vsup[(size_t)B*NW*PD*LTCAP];
__device__ float g_vbarn[B*NW*PD];
__device__ float g_qproj[(size_t)B*Q*PD*MSP];
__device__ float g_qprojc[(size_t)B*Q*PD*MSP];   // masked rows compacted, zero-padded
__device__ float g_vqn[(size_t)B*Q*PD*MSP];
__device__ unsigned long long g_rowpack[(size_t)B*Q*NW*MSP];
__device__ unsigned long long g_snear2pack[(size_t)B*Q*NW*LTCAP];
__device__ int   g_qmrows[B*Q*MSP];
__device__ int   g_qmcount[B*Q];
__device__ unsigned g_cmax[(size_t)B*Q*NW*MSP];
__device__ float g_logits[B*Q*NW];

__device__ __forceinline__ unsigned enc_f(float f){
  unsigned b=__float_as_uint(f);
  return (b&0x80000000u)? ~b : (b|0x80000000u);
}
__device__ __forceinline__ float dec_f(unsigned k){
  unsigned b=(k&0x80000000u)?(k^0x80000000u):~k;
  return __uint_as_float(b);
}
__device__ __forceinline__ unsigned long long pk_make(float v,int idx){
  return ((unsigned long long)enc_f(v)<<32)|(unsigned)~(unsigned)idx;
}
__device__ __forceinline__ int pk_idx(unsigned long long p){
  return (int)~(unsigned)(p&0xFFFFFFFFull);
}

// ---------------- init ------------------------------------------------------
__global__ void k_init(){
  int i=blockIdx.x*256+threadIdx.x;
  if (i<B*NJ) g_snearpack[i]=0ull;
  if (i<B*MU) g_unearpack[i]=0ull;
  if (i<B*Q*NW*MSP){ g_rowpack[i]=0ull; g_cmax[i]=0u; }
  if (i<B*Q*NW*LTCAP) g_snear2pack[i]=0ull;
  if (i==0) g_L[0]=0;
}

// ---------------- K1: inverse column norms ---------------------------------
__global__ void k_norms(const float* __restrict__ sup, const float* __restrict__ unl){
  int i=blockIdx.x*256+threadIdx.x;
  if (i<B*MU){
    int b=i/MU, m=i%MU, ui=m/HW, p=m%HW;
    const float* base=unl+((size_t)(b*U+ui)*C)*HW+p;
    float ss=0.f;
    for (int c=0;c<C;c++){ float x=base[(size_t)c*HW]; ss+=x*x; }
    g_rnu[i]=1.f/fmaxf(sqrtf(ss),1e-12f);
  }
  if (i<B*NJ){
    int b=i/NJ, j=i%NJ, n=j/MS, s=j%MS;
    const float* base=sup+((size_t)(b*NW+n)*C)*HW+s;
    float ss=0.f;
    for (int c=0;c<C;c++){ float x=base[(size_t)c*HW]; ss+=x*x; }
    g_rns[i]=1.f/fmaxf(sqrtf(ss),1e-12f);
  }
}

// ---------------- K2: u2s — col-split 6x; 64x128 tiles; shuffle argmaxes ----
__global__ __launch_bounds__(256) void k_u2s(const float* __restrict__ sup, const float* __restrict__ unl){
  int blk=blockIdx.x;
  int grp=blk%6; blk/=6;
  int rb=blk%138; int b=blk/138;
  int mb=rb*64;
  int tid=threadIdx.x, tm=tid>>4, tl=tid&15;
  int lane=tid&63, w=tid>>6;
  __shared__ __align__(16) float Ut[4096];     // [c][m] 16KB
  __shared__ __align__(16) float Pt[8192];     // [c][j] 32KB
  __shared__ unsigned long long colred[512];   // [w][128] 4KB
  int mv=min(64,MU-mb);
  for (int k=tid;k<4096;k+=256){
    int c=k>>6, mm=k&63; float v=0.f;
    if (mm<mv){ int m=mb+mm, ui=m/HW, p=m%HW; v=unl[((size_t)(b*U+ui)*C+c)*HW+p]*g_rnu[b*MU+m]; }
    Ut[c*64+mm]=v;
  }
  unsigned long long rowpk[4]={0ull,0ull,0ull,0ull};
  for (int t=0;t<3;t++){
    int j0=(grp*3+t)*128;
    int jv=min(128,NJ-j0);
    __syncthreads();
    for (int k=tid;k<8192;k+=256){
      int c=k>>7, jj=k&127; float v=0.f;
      if (jj<jv){ int j=j0+jj, n=j/MS, s=j%MS; v=sup[((size_t)(b*NW+n)*C+c)*HW+s]*g_rns[b*NJ+j]; }
      Pt[c*128+jj]=v;
    }
    __syncthreads();
    float s[4][8]={};
    for (int c=0;c<64;c++){
      float a[4],b0[4],b1[4];
      *(float4*)a =*(const float4*)&Ut[c*64+tm*4];
      *(float4*)b0=*(const float4*)&Pt[c*128+tl*4];
      *(float4*)b1=*(const float4*)&Pt[c*128+64+tl*4];
      #pragma unroll
      for (int i=0;i<4;i++)
        #pragma unroll
        for (int j=0;j<4;j++){ s[i][j]=fmaf(a[i],b0[j],s[i][j]); s[i][j+4]=fmaf(a[i],b1[j],s[i][j+4]); }
    }
    #pragma unroll
    for (int i=0;i<4;i++){
      if (tm*4+i<mv){
        unsigned long long p=rowpk[i];
        #pragma unroll
        for (int j=0;j<8;j++){
          int jj=(j<4)?(tl*4+j):(64+tl*4+(j-4));
          if (jj<jv){
            unsigned long long c2=pk_make(s[i][j],j0+jj);
            if (c2>p) p=c2;
          }
        }
        rowpk[i]=p;
      }
    }
    unsigned long long cpk[8];
    #pragma unroll
    for (int j=0;j<8;j++){
      unsigned long long p=0ull;
      #pragma unroll
      for (int i=0;i<4;i++){
        if (tm*4+i<mv){
          unsigned long long c2=pk_make(s[i][j],mb+tm*4+i);
          if (c2>p) p=c2;
        }
      }
      cpk[j]=p;
    }
    #pragma unroll
    for (int j=0;j<8;j++){
      unsigned long long o;
      o=__shfl_xor(cpk[j],16); if (o>cpk[j]) cpk[j]=o;
      o=__shfl_xor(cpk[j],32); if (o>cpk[j]) cpk[j]=o;
    }
    if ((lane>>4)==0){
      #pragma unroll
      for (int j=0;j<8;j++){
        int jj=(j<4)?(tl*4+j):(64+tl*4+(j-4));
        colred[w*128+jj]=cpk[j];
      }
    }
    __syncthreads();
    if (tid<128 && tid<jv){
      unsigned long long p=colred[tid];
      if (colred[128+tid]>p) p=colred[128+tid];
      if (colred[256+tid]>p) p=colred[256+tid];
      if (colred[384+tid]>p) p=colred[384+tid];
      if (p) atomicMax(&g_snearpack[b*NJ+j0+tid],p);
    }
  }
  #pragma unroll
  for (int i=0;i<4;i++){
    unsigned long long p=rowpk[i];
    #pragma unroll
    for (int mk=1;mk<16;mk<<=1){ unsigned long long o=__shfl_xor(p,mk); if (o>p) p=o; }
    if (tl==0 && tm*4+i<mv && p) atomicMax(&g_unearpack[b*MU+mb+tm*4+i],p);
  }
}

// ---------------- K4: mutual check + stable compaction; counts; L ----------
__global__ __launch_bounds__(256) void k_compact(){
  int b=blockIdx.x/NW, n=blockIdx.x%NW;
  int tid=threadIdx.x, lane=tid&63, w=tid>>6;
  __shared__ int wtot[4];
  int base=0;
  for (int m0=0;m0<MU;m0+=256){
    int m=m0+tid;
    bool flag=false;
    if (m<MU){
      int j=pk_idx(g_unearpack[b*MU+m]);
      flag=(j/MS==n) && (pk_idx(g_snearpack[b*NJ+j])==m);
    }
    unsigned long long bal=__ballot(flag);
    if (lane==0) wtot[w]=(int)__popcll(bal);
    __syncthreads();
    int wpre=0, tot=0;
    #pragma unroll
    for (int ww=0;ww<4;ww++){ if (ww<w) wpre+=wtot[ww]; tot+=wtot[ww]; }
    if (flag){
      int pre=(int)__popcll(bal&((1ull<<lane)-1ull));
      g_selidx[(b*NW+n)*LCAP+base+wpre+pre]=m;
    }
    base+=tot;
    __syncthreads();
  }
  if (tid==0){ g_counts[b*NW+n]=base; atomicMax(&g_L[0],base); }
}

// ---------------- K5: k_sup / v_sup (real cols only; o-split x2) ------------
__global__ __launch_bounds__(256) void k_kv(const float* __restrict__ sup, const float* __restrict__ unl,
                                            const float* __restrict__ kw, const float* __restrict__ vw){
  int blk=blockIdx.x;
  int os=blk&1; blk>>=1;
  int lb=blk%(LTCAP/64); blk/=(LTCAP/64);
  int n=blk%NW, b=blk/NW;
  int cnt=g_counts[b*NW+n];
  if (lb*64>=MS+cnt) return;
  int tid=threadIdx.x, lane=tid&63, w=tid>>6;
  __shared__ float F[4096];
  __shared__ const float* ptr_s[64];
  if (tid<64){
    int l=lb*64+tid;
    const float* p=nullptr;
    if (l<MS) p=&sup[((size_t)(b*NW+n)*C)*HW+l];
    else if (l<MS+cnt){
      int mg=g_selidx[(b*NW+n)*LCAP+(l-MS)];
      int ui=mg/HW, pp=mg%HW;
      p=&unl[((size_t)(b*U+ui)*C)*HW+pp];
    }
    ptr_s[tid]=p;
  }
  __syncthreads();
  for (int k=tid;k<4096;k+=256){
    int c=k>>6, ll=k&63;
    const float* p=ptr_s[ll];
    F[c*64+ll]=p?p[(size_t)c*HW]:0.f;
  }
  __syncthreads();
  int l=lb*64+lane;
  size_t ob=((size_t)(b*NW+n)*PD)*LTCAP+l;
  for (int oo=0;oo<8;oo++){
    int o=os*32+w*8+oo;
    float ka=0.f, va=0.f;
    for (int c=0;c<C;c++){ float f=F[c*64+lane]; ka=fmaf(kw[o*C+c],f,ka); va=fmaf(vw[o*C+c],f,va); }
    g_ksup[ob+(size_t)o*LTCAP]=ka;
    g_vsup[ob+(size_t)o*LTCAP]=va;
  }
}

// ---------------- K5b: normalized vbar = mean_l v_sup, L2-normalized --------
__global__ __launch_bounds__(256) void k_vbar(){
  int bn=blockIdx.x;
  int tid=threadIdx.x, lane=tid&63, w=tid>>6;
  int cnt=g_counts[bn];
  int Lt=MS+g_L[0];
  __shared__ float vb_s[64];
  for (int oo=0;oo<16;oo++){
    int o=w*16+oo;
    const float* row=&g_vsup[((size_t)bn*PD+o)*LTCAP];
    float s=0.f;
    for (int l=lane;l<MS+cnt;l+=64) s+=row[l];
    #pragma unroll
    for (int mk=1;mk<64;mk<<=1) s+=__shfl_xor(s,mk);
    if (lane==0) vb_s[o]=s/(float)Lt;
  }
  __syncthreads();
  if (tid<64){
    float v=vb_s[tid];
    float ss=v*v;
    #pragma unroll
    for (int mk=1;mk<64;mk<<=1) ss+=__shfl_xor(ss,mk);
    g_vbarn[bn*PD+tid]=v/(sqrtf(ss)+1e-16f);
  }
}

// ---------------- K6: q_proj / normalized v_query (256 thr, o-split) --------
__global__ __launch_bounds__(256) void k_qproj(const float* __restrict__ qx, const float* __restrict__ qw,
                                               const float* __restrict__ vw){
  int blk=blockIdx.x;
  int mt=blk%7; blk/=7;
  int bq=blk;
  int tid=threadIdx.x, lane=tid&63, w=tid>>6;
  __shared__ float F[4096];
  __shared__ float ssp[256];
  for (int k=tid;k<4096;k+=256){
    int c=k>>6, mm=k&63, m=mt*64+mm;
    F[c*64+mm]=(m<MS)?qx[((size_t)bq*C+c)*HW+m]:0.f;
  }
  __syncthreads();
  int m=mt*64+lane;
  size_t ob=(size_t)bq*PD*MSP+m;
  float va[16]; float ssl=0.f;
  for (int oo=0;oo<16;oo++){
    int o=w*16+oo;
    float qa=0.f, v=0.f;
    for (int c=0;c<C;c++){ float f=F[c*64+lane]; qa=fmaf(qw[o*C+c],f,qa); v=fmaf(vw[o*C+c],f,v); }
    g_qproj[ob+(size_t)o*MSP]=qa;
    va[oo]=v; ssl=fmaf(v,v,ssl);
  }
  ssp[tid]=ssl;
  __syncthreads();
  float ss=ssp[lane]+ssp[64+lane]+ssp[128+lane]+ssp[192+lane];
  float rn=1.f/(sqrtf(ss)+1e-16f);
  for (int oo=0;oo<16;oo++) g_vqn[ob+(size_t)(w*16+oo)*MSP]=va[oo]*rn;
}

// ---------------- K7: pass A — real cols only + analytic pad candidate ------
__global__ __launch_bounds__(256) void k_passA(){
  int blk=blockIdx.x;
  int mh=blk%4; blk/=4;
  int n=blk%NW; blk/=NW;
  int bq=blk; int b=bq/Q;
  int cnt=g_counts[b*NW+n];
  int Ltn=MS+cnt;
  int nch=(Ltn+63)>>6;
  int tid=threadIdx.x, tm=tid>>4, tl=tid&15;
  int lane=tid&63, w=tid>>6;
  int bqn=bq*NW+n;
  int m0=mh*128;
  __shared__ __align__(16) float Qt[8192];     // [o][mm] 32KB
  __shared__ __align__(16) float Kt[4096];     // [o][l]  16KB
  __shared__ unsigned long long colred[256];
  const size_t qb=(size_t)bq*PD*MSP;
  const size_t kb=(size_t)(b*NW+n)*PD*LTCAP;
  for (int k=tid;k<2048;k+=256){
    int o=k>>5, mq=k&31;
    int m=m0+mq*4;
    float4 v=make_float4(0.f,0.f,0.f,0.f);
    if (m<MSP) v=*(const float4*)&g_qproj[qb+(size_t)o*MSP+m];
    *(float4*)&Qt[o*128+mq*4]=v;
  }
  unsigned long long rowpk[8]={0ull,0ull,0ull,0ull,0ull,0ull,0ull,0ull};
  for (int lc=0;lc<nch;lc++){
    int l0=lc<<6, lv=min(64,Ltn-l0);
    __syncthreads();
    for (int k=tid;k<1024;k+=256){
      int o=k>>4, lq=k&15;
      *(float4*)&Kt[o*64+lq*4]=*(const float4*)&g_ksup[kb+(size_t)o*LTCAP+l0+lq*4];
    }
    __syncthreads();
    float s[8][4]={};
    for (int c=0;c<64;c++){
      float a[8],bv[4];
      *(float4*)&a[0]=*(const float4*)&Qt[c*128+tm*8];
      *(float4*)&a[4]=*(const float4*)&Qt[c*128+tm*8+4];
      *(float4*)bv=*(const float4*)&Kt[c*64+tl*4];
      #pragma unroll
      for (int i=0;i<8;i++)
        #pragma unroll
        for (int j=0;j<4;j++) s[i][j]=fmaf(a[i],bv[j],s[i][j]);
    }
    #pragma unroll
    for (int i=0;i<8;i++)
      #pragma unroll
      for (int j=0;j<4;j++) s[i][j]*=0.125f;
    #pragma unroll
    for (int i=0;i<8;i++){
      int m=m0+tm*8+i;
      if (m<MS){
        unsigned long long p=rowpk[i];
        #pragma unroll
        for (int j=0;j<4;j++){
          if (tl*4+j<lv){
            unsigned long long c2=pk_make(s[i][j],l0+tl*4+j);
            if (c2>p) p=c2;
          }
        }
        rowpk[i]=p;
      }
    }
    unsigned long long cpk[4];
    #pragma unroll
    for (int j=0;j<4;j++){
      unsigned long long p=0ull;
      #pragma unroll
      for (int i=0;i<8;i++){
        int m=m0+tm*8+i;
        if (m<MS){
          unsigned long long c2=pk_make(s[i][j],m);
          if (c2>p) p=c2;
        }
      }
      cpk[j]=p;
    }
    #pragma unroll
    for (int j=0;j<4;j++){
      unsigned long long o;
      o=__shfl_xor(cpk[j],16); if (o>cpk[j]) cpk[j]=o;
      o=__shfl_xor(cpk[j],32); if (o>cpk[j]) cpk[j]=o;
    }
    if ((lane>>4)==0){
      #pragma unroll
      for (int j=0;j<4;j++) colred[w*64+tl*4+j]=cpk[j];
    }
    __syncthreads();
    if (tid<64 && tid<lv){
      unsigned long long p=colred[tid];
      if (colred[64+tid]>p) p=colred[64+tid];
      if (colred[128+tid]>p) p=colred[128+tid];
      if (colred[192+tid]>p) p=colred[192+tid];
      if (p) atomicMax(&g_snear2pack[(size_t)bqn*LTCAP+l0+tid],p);
    }
  } // lc
  // analytic pad candidate: L-cnt all-zero columns, first at l=Ltn, value 0
  if (cnt<g_L[0]){
    unsigned long long pc=pk_make(0.0f,Ltn);
    #pragma unroll
    for (int i=0;i<8;i++){ if (pc>rowpk[i]) rowpk[i]=pc; }
  }
  #pragma unroll
  for (int i=0;i<8;i++){
    int m=m0+tm*8+i;
    unsigned long long p=rowpk[i];
    #pragma unroll
    for (int mk=1;mk<16;mk<<=1){ unsigned long long o=__shfl_xor(p,mk); if (o>p) p=o; }
    if (tl==0 && m<MS && p) atomicMax(&g_rowpack[(size_t)bqn*MSP+m],p);
  }
}

// ---------------- K8: q_mask + masked-row compaction + Q-row compaction -----
__global__ __launch_bounds__(256) void k_qmask(){
  int bq=blockIdx.x; int b=bq/Q;
  int tid=threadIdx.x, lane=tid&63, w=tid>>6;
  __shared__ int wtot[4];
  __shared__ int rows_sh[MSP];
  int base=0;
  for (int m0=0;m0<MS;m0+=256){
    int m=m0+tid;
    bool qm=false;
    if (m<MS){
      unsigned bhv=0u; unsigned long long bp=0ull; int bn=0;
      #pragma unroll
      for (int n=0;n<NW;n++){
        unsigned long long pk=g_rowpack[(size_t)(bq*NW+n)*MSP+m];
        unsigned hv=(unsigned)(pk>>32);
        if (hv>bhv){bhv=hv;bp=pk;bn=n;}
      }
      int bl=pk_idx(bp);
      int s2;
      if (bl>=MS+g_counts[b*NW+bn]) s2=0;   // all-zero pad column -> argmax m=0
      else s2=pk_idx(g_snear2pack[(size_t)(bq*NW+bn)*LTCAP+bl]);
      qm=(s2==m);
    }
    unsigned long long bal=__ballot(qm);
    if (lane==0) wtot[w]=(int)__popcll(bal);
    __syncthreads();
    int wpre=0, tot=0;
    #pragma unroll
    for (int ww=0;ww<4;ww++){ if (ww<w) wpre+=wtot[ww]; tot+=wtot[ww]; }
    if (qm){
      int pre=(int)__popcll(bal&((1ull<<lane)-1ull));
      g_qmrows[bq*MSP+base+wpre+pre]=m;
    }
    base+=tot;
    __syncthreads();
  }
  if (tid==0) g_qmcount[bq]=base;
  // ---- compact Q rows into g_qprojc (coalesced consumer layout) ----
  for (int r=tid;r<base;r+=256) rows_sh[r]=g_qmrows[bq*MSP+r];
  __syncthreads();
  int nmr=(base+63)&~63;
  size_t cb=(size_t)bq*PD*MSP;
  for (int o=0;o<PD;o++){
    const float* src=&g_qproj[cb+(size_t)o*MSP];
    float* dst=&g_qprojc[cb+(size_t)o*MSP];
    for (int rc=tid;rc<nmr;rc+=256)
      dst[rc]=(rc<base)?src[rows_sh[rc]]:0.f;
  }
}

// ---------------- K9: pass B — fixed-m*, LDS P round-trip (R4 structure) ----
__global__ __launch_bounds__(256) void k_passB(){
  int blk=blockIdx.x;
  int rt=blk%7; blk/=7;
  int n=blk%NW; blk/=NW;
  int bq=blk; int b=bq/Q;
  int nm=g_qmcount[bq];
  if (rt*64>=nm) return;
  int bqn=bq*NW+n;
  int cnt=g_counts[b*NW+n];
  int pads=g_L[0]-cnt;
  int Ltn=MS+cnt;
  int nch=(Ltn+63)>>6;
  int tid=threadIdx.x, tm=tid>>4, tl=tid&15;
  __shared__ __align__(16) float Qt[4096];     // [o][r] 16KB
  __shared__ __align__(16) float KV[64*67];    // K as [o][l] / V^T as [l][o] stride 67
  __shared__ __align__(16) float Pt[64*65];    // P rows / aligned rows
  const size_t cb=(size_t)bq*PD*MSP;
  const size_t kb=(size_t)(b*NW+n)*PD*LTCAP;
  // stage compacted Q rows (coalesced float4)
  for (int k=tid;k<1024;k+=256){
    int o=k>>4, rq=k&15;
    *(float4*)&Qt[o*64+rq*4]=*(const float4*)&g_qprojc[cb+(size_t)o*MSP+rt*64+rq*4];
  }
  // per-row softmax max (precomputed in passA rowpack, incl. pad candidate)
  float mst[4];
  #pragma unroll
  for (int i=0;i<4;i++){
    int rc=rt*64+tm*4+i;
    float m_=0.f;
    if (rc<nm){
      int mrow=g_qmrows[bq*MSP+rc];
      m_=dec_f((unsigned)(g_rowpack[(size_t)bqn*MSP+mrow]>>32));
    }
    mst[i]=m_;
  }
  float acc[4][4]={}; float lsl[4]={0.f,0.f,0.f,0.f};
  for (int lc=0;lc<nch;lc++){
    int l0=lc<<6, lv=min(64,Ltn-l0);
    __syncthreads();                 // Qt ready / prev-chunk PV reads done
    for (int k=tid;k<1024;k+=256){
      int o=k>>4, lq=k&15;
      *(float4*)&KV[o*64+lq*4]=*(const float4*)&g_ksup[kb+(size_t)o*LTCAP+l0+lq*4];
    }
    __syncthreads();
    float s[4][4]={};
    for (int c=0;c<64;c++){
      float a[4],bv[4];
      *(float4*)a =*(const float4*)&Qt[c*64+tm*4];
      *(float4*)bv=*(const float4*)&KV[c*64+tl*4];
      #pragma unroll
      for (int i=0;i<4;i++)
        #pragma unroll
        for (int j=0;j<4;j++) s[i][j]=fmaf(a[i],bv[j],s[i][j]);
    }
    // e = exp(s/8 - m*), masked beyond lv; accumulate local denom (linear!)
    #pragma unroll
    for (int i=0;i<4;i++)
      #pragma unroll
      for (int j=0;j<4;j++){
        float e=(tl*4+j<lv)?__expf(fmaf(s[i][j],0.125f,-mst[i])):0.f;
        s[i][j]=e; lsl[i]+=e;
      }
    __syncthreads();                 // all K reads done before V overwrite
    #pragma unroll
    for (int i=0;i<4;i++)
      #pragma unroll
      for (int j=0;j<4;j++) Pt[(tm*4+i)*65+tl*4+j]=s[i][j];
    for (int k=tid;k<4096;k+=256){
      int o=k>>6, ll=k&63;
      KV[ll*67+o]=g_vsup[kb+(size_t)o*LTCAP+l0+ll];
    }
    __syncthreads();
    for (int l4=0;l4<64;l4+=4){
      float p[4][4];
      #pragma unroll
      for (int i=0;i<4;i++)
        #pragma unroll
        for (int u=0;u<4;u++) p[i][u]=Pt[(tm*4+i)*65+l4+u];
      #pragma unroll
      for (int u=0;u<4;u++){
        float2 v01=*(const float2*)&KV[(l4+u)*67+tl*4];
        float2 v23=*(const float2*)&KV[(l4+u)*67+tl*4+2];
        #pragma unroll
        for (int i=0;i<4;i++){
          acc[i][0]=fmaf(p[i][u],v01.x,acc[i][0]);
          acc[i][1]=fmaf(p[i][u],v01.y,acc[i][1]);
          acc[i][2]=fmaf(p[i][u],v23.x,acc[i][2]);
          acc[i][3]=fmaf(p[i][u],v23.y,acc[i][3]);
        }
      }
    }
  } // lc
  // finalize: denom (+ pads·exp(-m*)), normalize, row L2 norm
  float rn_[4];
  #pragma unroll
  for (int i=0;i<4;i++){
    float v=lsl[i];
    #pragma unroll
    for (int mk=1;mk<16;mk<<=1) v+=__shfl_xor(v,mk);
    v+=(float)pads*__expf(-mst[i]);
    float inv=1.f/v;
    float ss=0.f;
    #pragma unroll
    for (int j=0;j<4;j++){ acc[i][j]*=inv; ss=fmaf(acc[i][j],acc[i][j],ss); }
    #pragma unroll
    for (int mk=1;mk<16;mk<<=1) ss+=__shfl_xor(ss,mk);
    rn_[i]=1.f/(sqrtf(ss)+1e-16f);
  }
  __syncthreads();                   // last PV reads done before Pt overwrite
  #pragma unroll
  for (int i=0;i<4;i++)
    #pragma unroll
    for (int j=0;j<4;j++) Pt[(tm*4+i)*65+tl*4+j]=acc[i][j];
  int rowok[4];
  #pragma unroll
  for (int i=0;i<4;i++) rowok[i]=(rt*64+tm*4+i<nm);
  for (int kt=0;kt<7;kt++){
    __syncthreads();
    for (int k=tid;k<1024;k+=256){
      int o=k>>4, kq=k&15;
      *(float4*)&KV[o*64+kq*4]=*(const float4*)&g_vqn[cb+(size_t)o*MSP+kt*64+kq*4];
    }
    __syncthreads();
    float d[4][4]={};
    for (int o=0;o<64;o++){
      float a[4], bv4[4];
      #pragma unroll
      for (int i=0;i<4;i++) a[i]=Pt[(tm*4+i)*65+o];
      *(float4*)bv4=*(const float4*)&KV[o*64+tl*4];
      #pragma unroll
      for (int i=0;i<4;i++)
        #pragma unroll
        for (int j=0;j<4;j++) d[i][j]=fmaf(a[i],bv4[j],d[i][j]);
    }
    #pragma unroll
    for (int j=0;j<4;j++){
      int kg2=kt*64+tl*4+j;
      float mv=NEGF;
      #pragma unroll
      for (int i=0;i<4;i++) if (rowok[i]) mv=fmaxf(mv,d[i][j]*rn_[i]);
      mv=fmaxf(mv,__shfl_xor(mv,16));
      mv=fmaxf(mv,__shfl_xor(mv,32));
      if (((tid>>4)&3)==0 && kg2<MS && mv>-1e37f)
        atomicMax(&g_cmax[(size_t)bqn*MSP+kg2],enc_f(mv));
    }
  }
}

// ---------------- K10: logits (with fused vbar contribution) ----------------
__global__ __launch_bounds__(256) void k_logits(){
  int bqn=blockIdx.x;
  int n=bqn%NW, bq=bqn/NW, b=bq/Q;
  int tid=threadIdx.x;
  int nm=g_qmcount[bq];
  __shared__ float red[256];
  __shared__ float vb_s[64];
  if (tid<64) vb_s[tid]=g_vbarn[(b*NW+n)*PD+tid];
  __syncthreads();
  const float* vq=&g_vqn[(size_t)bq*PD*MSP];
  float p=0.f;
  for (int k=tid;k<MS;k+=256){
    float v=dec_f(g_cmax[(size_t)bqn*MSP+k]);
    if (nm<MS){
      float d=0.f;
      for (int o=0;o<PD;o++) d=fmaf(vb_s[o],vq[(size_t)o*MSP+k],d);
      v=fmaxf(v,d);
    }
    p+=(v+1.f)*0.5f;
  }
  red[tid]=p; __syncthreads();
  for (int s=128;s;s>>=1){ if (tid<s) red[tid]+=red[tid+s]; __syncthreads(); }
  if (tid==0) g_logits[bqn]=red[0];
}

// ---------------- K11: NLL loss ---------------------------------------------
__global__ void k_loss(const int* __restrict__ qy, float* __restrict__ out){
  int t=threadIdx.x;
  float lp=0.f;
  if (t<B*Q){
    int y=qy[t];
    float xv[NW]; float mxv=NEGF;
    #pragma unroll
    for (int n=0;n<NW;n++){ xv[n]=g_logits[t*NW+n]*5.f; mxv=fmaxf(mxv,xv[n]); }
    float s=0.f, xy=0.f;
    #pragma unroll
    for (int n=0;n<NW;n++){ s+=__expf(xv[n]-mxv); if (n==y) xy=xv[n]; }
    lp=xy-mxv-logf(s);
  }
  #pragma unroll
  for (int off=32;off;off>>=1) lp+=__shfl_down(lp,off);
  if (t==0) out[0]=-lp/(float)(B*Q);
}

extern "C" void kernel_launch(void* const* d_in, const int* in_sizes, int n_in,
                              void* d_out, int out_size, void* d_ws, size_t ws_size,
                              hipStream_t stream) {
  (void)in_sizes; (void)n_in; (void)out_size; (void)d_ws; (void)ws_size;
  const float* sup=(const float*)d_in[0];
  const float* qx =(const float*)d_in[2];
  const int*   qy =(const int*)d_in[3];
  const float* unl=(const float*)d_in[4];
  const float* kw =(const float*)d_in[5];
  const float* qw =(const float*)d_in[6];
  const float* vw =(const float*)d_in[7];
  float* out=(float*)d_out;

  k_init   <<<1575,256,0,stream>>>();
  k_norms  <<<69,256,0,stream>>>(sup,unl);
  k_u2s    <<<B*138*6,256,0,stream>>>(sup,unl);
  k_compact<<<B*NW,256,0,stream>>>();
  k_kv     <<<B*NW*(LTCAP/64)*2,256,0,stream>>>(sup,unl,kw,vw);
  k_vbar   <<<B*NW,256,0,stream>>>();
  k_qproj  <<<B*Q*7,256,0,stream>>>(qx,qw,vw);
  k_passA  <<<B*Q*NW*4,256,0,stream>>>();
  k_qmask  <<<B*Q,256,0,stream>>>();
  k_passB  <<<B*Q*NW*7,256,0,stream>>>();
  k_logits <<<B*Q*NW,256,0,stream>>>();
  k_loss   <<<1,64,0,stream>>>(qy,out);
}